// Round 2
// baseline (12198.484 us; speedup 1.0000x reference)
//
#include <hip/hip_runtime.h>

#define B_  256
#define T_  1024
#define H_  64

// fast sigmoid/tanh via v_exp_f32 + v_rcp_f32 (rel err ~1e-6, threshold 2.86e-4)
__device__ __forceinline__ float fast_sigmoid(float x) {
    float e = __builtin_amdgcn_exp2f(-1.4426950408889634f * x);
    return __builtin_amdgcn_rcpf(1.0f + e);
}
__device__ __forceinline__ float fast_tanh(float x) {
    // tanh(x) = 1 - 2/(exp(2x)+1); exp(2x) = exp2(x * 2*log2(e)). Saturates cleanly.
    float e = __builtin_amdgcn_exp2f(2.8853900817779268f * x);
    return 1.0f - 2.0f * __builtin_amdgcn_rcpf(1.0f + e);
}

// Diagonal pipeline over 5 LSTM layers: at step s, layer l processes t = s - l.
// One block per batch row; 640 threads = 2 waves per layer.
// Thread (l, k) k in [0,128) owns gate rows k and k+128 of layer l, weights in
// registers (4*64 = 256 fp32). Wave 2l (k<64) owns rows j (i-gate) and j+128
// (g-gate) and performs the cell update for hidden unit j; wave 2l+1 passes its
// f/o gate values through LDS.
__global__ __launch_bounds__(640, 1)
void lstm5_fused(const float* __restrict__ x,      // [B,T]
                 const float* __restrict__ w_ih0,  // [256]
                 const float* __restrict__ w_ihr,  // [4,256,64]
                 const float* __restrict__ w_hh,   // [5,256,64]
                 const float* __restrict__ b_ih,   // [5,256]
                 const float* __restrict__ b_hh,   // [5,256]
                 float* __restrict__ h4out)        // [B,T,64]
{
    const int b   = blockIdx.x;
    const int tid = threadIdx.x;
    const int l   = tid >> 7;        // layer 0..4 (wave-pair)
    const int k   = tid & 127;       // gate-row pair index
    const int j   = k & 63;          // hidden unit
    const bool owner = (k < 64);     // wave 2l lane j: does activation for unit j

    __shared__ __align__(16) float h_s[5][H_];   // recurrent h per layer
    __shared__ float fo_s[5][128];               // f at [l][j], o at [l][64+j]

    // ---- weights into registers ----
    float uA[H_], uB[H_];            // w_hh rows k, k+128
    float wA[H_], wB[H_];            // w_ih rows k, k+128 (layers 1..4)
    float w0A = 0.f, w0B = 0.f;      // layer-0 scalar input weights

    {
        const float* whh_l = w_hh + (long)l * 256 * H_;
        const float4* pA = (const float4*)(whh_l + (long)k * H_);
        const float4* pB = (const float4*)(whh_l + (long)(k + 128) * H_);
        #pragma unroll
        for (int q = 0; q < 16; ++q) {
            float4 a = pA[q], c4 = pB[q];
            uA[4*q+0]=a.x;  uA[4*q+1]=a.y;  uA[4*q+2]=a.z;  uA[4*q+3]=a.w;
            uB[4*q+0]=c4.x; uB[4*q+1]=c4.y; uB[4*q+2]=c4.z; uB[4*q+3]=c4.w;
        }
    }
    if (l == 0) {
        w0A = w_ih0[k];
        w0B = w_ih0[k + 128];
    } else {
        const float* wih_l = w_ihr + (long)(l - 1) * 256 * H_;
        const float4* qA = (const float4*)(wih_l + (long)k * H_);
        const float4* qB = (const float4*)(wih_l + (long)(k + 128) * H_);
        #pragma unroll
        for (int q = 0; q < 16; ++q) {
            float4 a = qA[q], c4 = qB[q];
            wA[4*q+0]=a.x;  wA[4*q+1]=a.y;  wA[4*q+2]=a.z;  wA[4*q+3]=a.w;
            wB[4*q+0]=c4.x; wB[4*q+1]=c4.y; wB[4*q+2]=c4.z; wB[4*q+3]=c4.w;
        }
    }
    const float biasA = b_ih[l*256 + k]       + b_hh[l*256 + k];
    const float biasB = b_ih[l*256 + k + 128] + b_hh[l*256 + k + 128];

    float c = 0.f;
    if (owner) h_s[l][j] = 0.f;
    __syncthreads();

    float x_cur = (l == 0) ? x[(long)b * T_] : 0.f;

    for (int s = 0; s < T_ + 4; ++s) {
        const int t = s - l;
        const bool active = ((unsigned)t < (unsigned)T_);

        // prefetch next scalar input for layer 0 (hidden by the gate matmul)
        float x_nxt = 0.f;
        if (l == 0 && s + 1 < T_) x_nxt = x[(long)b * T_ + s + 1];

        float gA = 0.f, gB = 0.f;
        if (active) {
            float a0 = biasA, a1 = 0.f, a2 = 0.f, a3 = 0.f;
            float c0 = biasB, c1 = 0.f, c2 = 0.f, c3 = 0.f;
            const float4* h4v = (const float4*)h_s[l];
            if (l == 0) {
                a0 += w0A * x_cur;
                c0 += w0B * x_cur;
                #pragma unroll
                for (int q = 0; q < 16; ++q) {
                    float4 hv = h4v[q];
                    a0 += uA[4*q+0]*hv.x; a1 += uA[4*q+1]*hv.y;
                    a2 += uA[4*q+2]*hv.z; a3 += uA[4*q+3]*hv.w;
                    c0 += uB[4*q+0]*hv.x; c1 += uB[4*q+1]*hv.y;
                    c2 += uB[4*q+2]*hv.z; c3 += uB[4*q+3]*hv.w;
                }
            } else {
                const float4* xv4 = (const float4*)h_s[l - 1];  // input = h of layer below
                #pragma unroll
                for (int q = 0; q < 16; ++q) {
                    float4 xv = xv4[q];
                    float4 hv = h4v[q];
                    a0 += wA[4*q+0]*xv.x; a1 += wA[4*q+1]*xv.y;
                    a2 += wA[4*q+2]*xv.z; a3 += wA[4*q+3]*xv.w;
                    a0 += uA[4*q+0]*hv.x; a1 += uA[4*q+1]*hv.y;
                    a2 += uA[4*q+2]*hv.z; a3 += uA[4*q+3]*hv.w;
                    c0 += wB[4*q+0]*xv.x; c1 += wB[4*q+1]*xv.y;
                    c2 += wB[4*q+2]*xv.z; c3 += wB[4*q+3]*xv.w;
                    c0 += uB[4*q+0]*hv.x; c1 += uB[4*q+1]*hv.y;
                    c2 += uB[4*q+2]*hv.z; c3 += uB[4*q+3]*hv.w;
                }
            }
            gA = (a0 + a1) + (a2 + a3);
            gB = (c0 + c1) + (c2 + c3);
            if (!owner) {                 // wave 2l+1: rows 64+j (f), 192+j (o)
                fo_s[l][j]      = gA;
                fo_s[l][64 + j] = gB;
            }
        }
        __syncthreads();

        if (active && owner) {            // wave 2l lane j: i=gA, g=gB in registers
            float i_ = fast_sigmoid(gA);
            float g_ = fast_tanh(gB);
            float f_ = fast_sigmoid(fo_s[l][j]);
            float o_ = fast_sigmoid(fo_s[l][64 + j]);
            c = f_ * c + i_ * g_;
            float h = o_ * fast_tanh(c);
            h_s[l][j] = h;
            if (l == 4) h4out[((long)b * T_ + t) * H_ + j] = h;
        }
        __syncthreads();

        if (l == 0) x_cur = x_nxt;
    }
}

// out[r] = W2 @ relu(W1 @ relu(h_r) + b1) + b2, one thread per (b,t) row.
__global__ __launch_bounds__(256, 1)
void mlp_head_kernel(const float* __restrict__ hbuf,  // [B*T, H]
                     const float* __restrict__ W1,    // [H, H]
                     const float* __restrict__ b1,    // [H]
                     const float* __restrict__ W2,    // [1, H]
                     const float* __restrict__ b2,    // [1]
                     float* __restrict__ out)         // [B*T]
{
    __shared__ __align__(16) float W1_s[H_ * H_];
    __shared__ float b1_s[H_];
    __shared__ float W2_s[H_];
    const int tid = threadIdx.x;

    #pragma unroll
    for (int i = 0; i < (H_ * H_ / 4) / 256; ++i)
        ((float4*)W1_s)[i * 256 + tid] = ((const float4*)W1)[i * 256 + tid];
    if (tid < H_) { b1_s[tid] = b1[tid]; W2_s[tid] = W2[tid]; }
    __syncthreads();
    const float b2v = b2[0];

    const long r = (long)blockIdx.x * 256 + tid;
    if (r >= (long)B_ * T_) return;

    float4 row4[16];
    const float4* src = (const float4*)(hbuf + r * H_);
    #pragma unroll
    for (int kk = 0; kk < 16; ++kk) {
        float4 v = src[kk];
        row4[kk] = make_float4(fmaxf(v.x, 0.f), fmaxf(v.y, 0.f),
                               fmaxf(v.z, 0.f), fmaxf(v.w, 0.f));
    }

    float acc = 0.f;
    for (int jj = 0; jj < H_; ++jj) {
        const float4* w4 = (const float4*)&W1_s[jj * H_];
        float a0 = 0.f, a1 = 0.f, a2 = 0.f, a3 = 0.f;
        #pragma unroll
        for (int kk = 0; kk < 16; ++kk) {
            float4 w = w4[kk];
            a0 += row4[kk].x * w.x; a1 += row4[kk].y * w.y;
            a2 += row4[kk].z * w.z; a3 += row4[kk].w * w.w;
        }
        float y = b1_s[jj] + (a0 + a1) + (a2 + a3);
        y = fmaxf(y, 0.f);
        acc += y * W2_s[jj];
    }
    out[r] = acc + b2v;
}

extern "C" void kernel_launch(void* const* d_in, const int* in_sizes, int n_in,
                              void* d_out, int out_size, void* d_ws, size_t ws_size,
                              hipStream_t stream) {
    const float* x     = (const float*)d_in[0];   // [B,T,1]
    const float* w_ih0 = (const float*)d_in[1];   // [4H,1]
    const float* w_ihr = (const float*)d_in[2];   // [L-1,4H,H]
    const float* w_hh  = (const float*)d_in[3];   // [L,4H,H]
    const float* b_ih  = (const float*)d_in[4];   // [L,4H]
    const float* b_hh  = (const float*)d_in[5];   // [L,4H]
    const float* W1    = (const float*)d_in[6];   // [H,H]
    const float* b1    = (const float*)d_in[7];   // [H]
    const float* W2    = (const float*)d_in[8];   // [1,H]
    const float* b2    = (const float*)d_in[9];   // [1]
    // d_in[10] = future (0)

    float* out = (float*)d_out;
    float* buf = (float*)d_ws;                    // [B,T,H] fp32 = 64 MB

    lstm5_fused<<<dim3(B_), dim3(640), 0, stream>>>(
        x, w_ih0, w_ihr, w_hh, b_ih, b_hh, buf);

    mlp_head_kernel<<<dim3((B_ * T_) / 256), dim3(256), 0, stream>>>(
        buf, W1, b1, W2, b2, out);
}

// Round 3
// 11907.230 us; speedup vs baseline: 1.0245x; 1.0245x over previous
//
#include <hip/hip_runtime.h>

#define B_ 256
#define T_ 1024
#define H_ 64

// fast sigmoid/tanh via v_exp_f32 + v_rcp_f32 (validated in R2: absmax 0.0)
__device__ __forceinline__ float fast_sigmoid(float x) {
    float e = __builtin_amdgcn_exp2f(-1.4426950408889634f * x);
    return __builtin_amdgcn_rcpf(1.0f + e);
}
__device__ __forceinline__ float fast_tanh(float x) {
    float e = __builtin_amdgcn_exp2f(2.8853900817779268f * x);
    return 1.0f - 2.0f * __builtin_amdgcn_rcpf(1.0f + e);
}

// v += dpp_shuffle(v); CTRL: 0xB1 = quad_perm[1,0,3,2] (xor1),
// 0x4E = quad_perm[2,3,0,1] (xor2), 0x141 = ROW_HALF_MIRROR (xor7 within 8;
// equals xor4 once bits 0-1 are already reduced).
template<int CTRL>
__device__ __forceinline__ float dpp_addf(float v) {
    int vi = __builtin_bit_cast(int, v);
    int sh = __builtin_amdgcn_update_dpp(0, vi, CTRL, 0xF, 0xF, true);
    return v + __builtin_bit_cast(float, sh);
}

// One block per batch row, 512 threads.
// Combined input vector v = [x_t (64, layers 1-4 only) | h_{t-1} (64)], split
// into 16-float chunks. Thread = (kc = chunk, rg = row-group): owns ROWS gate
// rows' weights for its chunk in REGISTERS (64 floats, asm-pinned), ingests its
// chunk once per step (4 ds_read_b128, bank-rotated), does 16 FMAs/row, then
// DPP-reduces the NCH partials per row across lanes. Lane kc==0 writes gates.
// Wave 0 (threads 0-63) does the pointwise cell update.
template<bool L0>
__global__ __attribute__((amdgpu_flat_work_group_size(512, 512),
                          amdgpu_waves_per_eu(2, 2)))
void lstm_layer_v3(const float* x_in,               // L0: [B,T]; else [B,T,H] (may alias h_out)
                   float* h_out,                     // [B,T,H]
                   const float* __restrict__ w_ih,   // L0: [256]; else [256,64]
                   const float* __restrict__ w_hh,   // [256,64]
                   const float* __restrict__ b_ih,   // [256]
                   const float* __restrict__ b_hh)   // [256]
{
    constexpr int NCH  = L0 ? 4 : 8;   // 16-float chunks in v
    constexpr int ROWS = NCH / 2;      // gate rows per thread (2 or 4)

    const int b   = blockIdx.x;
    const int tid = threadIdx.x;
    const int kc  = tid & (NCH - 1);
    const int rg  = tid >> (L0 ? 2 : 3);   // row group: [0, 256/ROWS)

    __shared__ __align__(16) float xh_s[2][L0 ? H_ : 2 * H_];
    __shared__ __align__(16) float gates_s[256];

    // ---- weights for (rows, chunk) into registers ----
    float4 wt[ROWS][4];
    #pragma unroll
    for (int r = 0; r < ROWS; ++r) {
        const int row = ROWS * rg + r;
        #pragma unroll
        for (int q = 0; q < 4; ++q) {
            const float* src;
            if (L0)          src = w_hh + row * H_ + kc * 16 + 4 * q;
            else if (kc < 4) src = w_ih + row * H_ + kc * 16 + 4 * q;
            else             src = w_hh + row * H_ + (kc - 4) * 16 + 4 * q;
            wt[r][q] = *(const float4*)src;
        }
    }
    // pin in VGPRs: opaque defs -> not rematerializable, must stay resident
    #pragma unroll
    for (int r = 0; r < ROWS; ++r)
        #pragma unroll
        for (int q = 0; q < 4; ++q)
            asm volatile("" : "+v"(wt[r][q].x), "+v"(wt[r][q].y),
                             "+v"(wt[r][q].z), "+v"(wt[r][q].w));

    // ---- activation-thread state (threads 0-63) ----
    float c_st = 0.f;
    float bias_i = 0.f, bias_f = 0.f, bias_g = 0.f, bias_o = 0.f;
    float w0i = 0.f, w0f = 0.f, w0g = 0.f, w0o = 0.f;
    float xt = 0.f;
    if (tid < H_) {
        bias_i = b_ih[tid]          + b_hh[tid];
        bias_f = b_ih[H_ + tid]     + b_hh[H_ + tid];
        bias_g = b_ih[2 * H_ + tid] + b_hh[2 * H_ + tid];
        bias_o = b_ih[3 * H_ + tid] + b_hh[3 * H_ + tid];
        if (L0) {
            w0i = w_ih[tid];           w0f = w_ih[H_ + tid];
            w0g = w_ih[2 * H_ + tid];  w0o = w_ih[3 * H_ + tid];
            xt  = x_in[(long)b * T_];
            xh_s[0][tid] = 0.f;                                  // h = 0
        } else {
            xh_s[0][tid]      = x_in[((long)b * T_) * H_ + tid]; // x_0
            xh_s[0][H_ + tid] = 0.f;                             // h = 0
        }
    }
    __syncthreads();

    for (int t = 0; t < T_; ++t) {
        const int rb = t & 1;

        // ---- prefetch next input (issued before FMA work hides latency) ----
        float xn = 0.f;
        if (L0) {
            if (tid < H_ && t + 1 < T_) xn = x_in[(long)b * T_ + t + 1];
        } else {
            if (tid < H_ && t + 1 < T_)
                xn = x_in[((long)b * T_ + t + 1) * H_ + tid];
        }

        // ---- ingest this thread's chunk (bank-rotated quarter order) ----
        const float4* xv = (const float4*)xh_s[rb];
        float4 hc[4];
        #pragma unroll
        for (int i2 = 0; i2 < 4; ++i2) {
            int q = (kc + i2) & 3;
            hc[q] = xv[kc * 4 + q];
        }

        // ---- partial dots: ROWS rows x 16 k ----
        float acc[ROWS];
        #pragma unroll
        for (int r = 0; r < ROWS; ++r) {
            float s0 = 0.f, s1 = 0.f, s2 = 0.f, s3 = 0.f;
            #pragma unroll
            for (int q = 0; q < 4; ++q) {
                s0 += wt[r][q].x * hc[q].x;
                s1 += wt[r][q].y * hc[q].y;
                s2 += wt[r][q].z * hc[q].z;
                s3 += wt[r][q].w * hc[q].w;
            }
            acc[r] = (s0 + s1) + (s2 + s3);
        }

        // ---- DPP all-reduce over the NCH chunk lanes ----
        #pragma unroll
        for (int r = 0; r < ROWS; ++r) {
            acc[r] = dpp_addf<0xB1>(acc[r]);          // xor 1
            acc[r] = dpp_addf<0x4E>(acc[r]);          // xor 2
            if constexpr (!L0) acc[r] = dpp_addf<0x141>(acc[r]);  // xor 4 (half mirror)
        }

        if (kc == 0) {
            if constexpr (L0) {
                *(float2*)&gates_s[2 * rg] = make_float2(acc[0], acc[1]);
            } else {
                *(float4*)&gates_s[4 * rg] = make_float4(acc[0], acc[1], acc[2], acc[3]);
            }
        }
        __syncthreads();

        // ---- pointwise cell update (PyTorch gate order i,f,g,o) ----
        if (tid < H_) {
            float gi = gates_s[tid]          + bias_i;
            float gf = gates_s[H_ + tid]     + bias_f;
            float gg = gates_s[2 * H_ + tid] + bias_g;
            float go = gates_s[3 * H_ + tid] + bias_o;
            if constexpr (L0) {
                gi += w0i * xt; gf += w0f * xt; gg += w0g * xt; go += w0o * xt;
            }
            float i_ = fast_sigmoid(gi);
            float f_ = fast_sigmoid(gf);
            float g_ = fast_tanh(gg);
            float o_ = fast_sigmoid(go);
            c_st = f_ * c_st + i_ * g_;
            float h = o_ * fast_tanh(c_st);
            const int wb = rb ^ 1;
            if constexpr (L0) {
                xh_s[wb][tid] = h;
            } else {
                xh_s[wb][H_ + tid] = h;
                xh_s[wb][tid]      = xn;   // next step's input row
            }
            h_out[((long)b * T_ + t) * H_ + tid] = h;
        }
        if (L0) xt = xn;
        __syncthreads();
    }
}

// MLP head: one thread per (b,t) row. W1/b1/W2 accesses are wave-uniform ->
// compiler emits scalar loads (zero LDS traffic); row stays in VGPRs (pinned).
__global__ __launch_bounds__(256)
void mlp_head_v2(const float* __restrict__ hbuf,  // [B*T, H]
                 const float* __restrict__ W1,    // [H, H]
                 const float* __restrict__ b1,    // [H]
                 const float* __restrict__ W2,    // [H]
                 const float* __restrict__ b2,    // [1]
                 float* __restrict__ out)         // [B*T]
{
    const long r = (long)blockIdx.x * 256 + threadIdx.x;

    float row[H_];
    const float4* src = (const float4*)(hbuf + r * H_);
    #pragma unroll
    for (int q = 0; q < 16; ++q) {
        float4 v = src[q];
        row[4 * q + 0] = fmaxf(v.x, 0.f);
        row[4 * q + 1] = fmaxf(v.y, 0.f);
        row[4 * q + 2] = fmaxf(v.z, 0.f);
        row[4 * q + 3] = fmaxf(v.w, 0.f);
    }
    #pragma unroll
    for (int q = 0; q < 16; ++q)
        asm volatile("" : "+v"(row[4*q]), "+v"(row[4*q+1]),
                         "+v"(row[4*q+2]), "+v"(row[4*q+3]));

    float acc = b2[0];
    #pragma unroll 4
    for (int j = 0; j < H_; ++j) {
        const float* wrow = W1 + j * H_;   // wave-uniform -> s_load
        float s0 = 0.f, s1 = 0.f, s2 = 0.f, s3 = 0.f;
        #pragma unroll
        for (int q = 0; q < 16; ++q) {
            s0 += row[4 * q + 0] * wrow[4 * q + 0];
            s1 += row[4 * q + 1] * wrow[4 * q + 1];
            s2 += row[4 * q + 2] * wrow[4 * q + 2];
            s3 += row[4 * q + 3] * wrow[4 * q + 3];
        }
        float y = fmaxf(b1[j] + (s0 + s1) + (s2 + s3), 0.f);
        acc += y * W2[j];
    }
    out[r] = acc;
}

extern "C" void kernel_launch(void* const* d_in, const int* in_sizes, int n_in,
                              void* d_out, int out_size, void* d_ws, size_t ws_size,
                              hipStream_t stream) {
    const float* x     = (const float*)d_in[0];   // [B,T,1]
    const float* w_ih0 = (const float*)d_in[1];   // [256]
    const float* w_ihr = (const float*)d_in[2];   // [4,256,64]
    const float* w_hh  = (const float*)d_in[3];   // [5,256,64]
    const float* b_ih  = (const float*)d_in[4];   // [5,256]
    const float* b_hh  = (const float*)d_in[5];   // [5,256]
    const float* W1    = (const float*)d_in[6];   // [64,64]
    const float* b1    = (const float*)d_in[7];   // [64]
    const float* W2    = (const float*)d_in[8];   // [64]
    const float* b2    = (const float*)d_in[9];   // [1]
    // d_in[10] = future (0)

    float* out = (float*)d_out;
    float* buf = (float*)d_ws;                    // [B,T,64] fp32 = 64 MB

    // layer 0 (scalar input)
    lstm_layer_v3<true><<<dim3(B_), dim3(512), 0, stream>>>(
        x, buf, w_ih0, w_hh, b_ih, b_hh);

    // layers 1..4, in-place on buf (row t+1 is read a step before row t is written)
    for (int l = 1; l < 5; ++l) {
        lstm_layer_v3<false><<<dim3(B_), dim3(512), 0, stream>>>(
            buf, buf,
            w_ihr + (long)(l - 1) * 256 * H_,
            w_hh  + (long)l * 256 * H_,
            b_ih  + (long)l * 256,
            b_hh  + (long)l * 256);
    }

    mlp_head_v2<<<dim3((B_ * T_) / 256), dim3(256), 0, stream>>>(
        buf, W1, b1, W2, b2, out);
}

// Round 4
// 2871.872 us; speedup vs baseline: 4.2476x; 4.1462x over previous
//
#include <hip/hip_runtime.h>

#define B_ 256
#define T_ 1024
#define H_ 64

typedef float f32x2 __attribute__((ext_vector_type(2)));
typedef float f32x4 __attribute__((ext_vector_type(4)));

// fast sigmoid/tanh via v_exp_f32 + v_rcp_f32 (correctness-validated R2/R3: absmax 0.0)
__device__ __forceinline__ float fast_sigmoid(float x) {
    float e = __builtin_amdgcn_exp2f(-1.4426950408889634f * x);
    return __builtin_amdgcn_rcpf(1.0f + e);
}
__device__ __forceinline__ float fast_tanh(float x) {
    float e = __builtin_amdgcn_exp2f(2.8853900817779268f * x);
    return 1.0f - 2.0f * __builtin_amdgcn_rcpf(1.0f + e);
}

// butterfly add via DPP (validated R3): 0xB1=xor1, 0x4E=xor2, 0x141=half-mirror(=xor4 after 1,2)
template<int CTRL>
__device__ __forceinline__ float dpp_addf(float v) {
    int vi = __builtin_bit_cast(int, v);
    int sh = __builtin_amdgcn_update_dpp(0, vi, CTRL, 0xF, 0xF, true);
    return v + __builtin_bit_cast(float, sh);
}

__device__ __forceinline__ f32x2 lo4(f32x4 v) { return __builtin_shufflevector(v, v, 0, 1); }
__device__ __forceinline__ f32x2 hi4(f32x4 v) { return __builtin_shufflevector(v, v, 2, 3); }

// One block per batch row. Combined input v = [x_t (layers>0) | h_{t-1}], split in
// 16-float chunks PADDED to 20 floats (80 B) in LDS -> the NCH distinct chunk
// addresses per ds_read_b128 hit disjoint bank quads (conflict-free).
// Thread (j, kc): owns all 4 gate rows {j,64+j,128+j,192+j} x chunk kc, weights
// asm-pinned in VGPRs (64 floats, proven resident in R3 via FETCH_SIZE).
// DPP all-reduce over the NCH chunk lanes; lane kc==0 then applies the cell
// update for unit j directly (no gates round-trip, single barrier per step).
template<bool L0>
__global__ __attribute__((amdgpu_flat_work_group_size(L0 ? 256 : 512, L0 ? 256 : 512),
                          amdgpu_waves_per_eu(2)))
void lstm_layer_v4(const float* x_in,                // L0: [B,T]; else [B,T,H] (aliases h_out)
                   float* h_out,                     // [B,T,H]
                   const float* __restrict__ w_ih,   // L0: [256]; else [256,64]
                   const float* __restrict__ w_hh,   // [256,64]
                   const float* __restrict__ b_ih,   // [256]
                   const float* __restrict__ b_hh)   // [256]
{
    constexpr int NCH = L0 ? 4 : 8;    // 16-float chunks in v
    const int b   = blockIdx.x;
    const int tid = threadIdx.x;
    const int kc  = tid & (NCH - 1);
    const int j   = tid >> (L0 ? 2 : 3);   // hidden unit [0,64)

    __shared__ __align__(16) float xh[2][NCH * 20];   // padded chunks, double-buffered

    // ---- weights (4 gate rows of unit j, chunk kc) into pinned registers ----
    f32x4 wt[4][4];
    #pragma unroll
    for (int r = 0; r < 4; ++r) {
        const int row = r * H_ + j;
        const float* base;
        if (L0)           base = w_hh + row * H_ + kc * 16;
        else if (kc < 4)  base = w_ih + row * H_ + kc * 16;
        else              base = w_hh + row * H_ + (kc - 4) * 16;
        #pragma unroll
        for (int q = 0; q < 4; ++q)
            wt[r][q] = *(const f32x4*)(base + 4 * q);
    }
    #pragma unroll
    for (int r = 0; r < 4; ++r)
        #pragma unroll
        for (int q = 0; q < 4; ++q)
            asm volatile("" : "+v"(wt[r][q]));

    float bias0 = 0.f, bias1 = 0.f, bias2 = 0.f, bias3 = 0.f;
    float w00 = 0.f, w01 = 0.f, w02 = 0.f, w03 = 0.f;
    if (kc == 0) {
        bias0 = b_ih[0 * H_ + j] + b_hh[0 * H_ + j];
        bias1 = b_ih[1 * H_ + j] + b_hh[1 * H_ + j];
        bias2 = b_ih[2 * H_ + j] + b_hh[2 * H_ + j];
        bias3 = b_ih[3 * H_ + j] + b_hh[3 * H_ + j];
        if (L0) {
            w00 = w_ih[0 * H_ + j]; w01 = w_ih[1 * H_ + j];
            w02 = w_ih[2 * H_ + j]; w03 = w_ih[3 * H_ + j];
        }
    }
    float c_st = 0.f;
    float xt = L0 ? x_in[(long)b * T_] : 0.f;   // wave-uniform scalar for L0

    if (tid < H_) {
        if (L0) {
            xh[0][(tid >> 4) * 20 + (tid & 15)] = 0.f;                            // h=0
        } else {
            xh[0][(tid >> 4) * 20 + (tid & 15)] = x_in[((long)b * T_) * H_ + tid]; // x_0
            xh[0][80 + (tid >> 4) * 20 + (tid & 15)] = 0.f;                        // h=0
        }
    }
    __syncthreads();

    for (int t = 0; t < T_; ++t) {
        const int rb = t & 1;
        const int wb = rb ^ 1;

        // ---- prefetch next input (latency hidden behind the matvec) ----
        float xn = 0.f;
        if (L0) {
            if (t + 1 < T_) xn = x_in[(long)b * T_ + t + 1];          // uniform -> s_load
        } else {
            if (kc == 1 && t + 1 < T_)
                xn = x_in[((long)b * T_ + t + 1) * H_ + j];
        }

        // ---- ingest chunk kc (4 conflict-free ds_read_b128, fixed order) ----
        const f32x4* xv = (const f32x4*)&xh[rb][kc * 20];
        f32x4 h0 = xv[0], h1 = xv[1], h2 = xv[2], h3 = xv[3];

        // ---- 4 gate rows x 16 k, packed fp32 FMA ----
        float acc0, acc1, acc2, acc3;
        #pragma unroll
        for (int r = 0; r < 4; ++r) {
            f32x2 a = {0.f, 0.f}, d = {0.f, 0.f};
            a = __builtin_elementwise_fma(lo4(wt[r][0]), lo4(h0), a);
            d = __builtin_elementwise_fma(hi4(wt[r][0]), hi4(h0), d);
            a = __builtin_elementwise_fma(lo4(wt[r][1]), lo4(h1), a);
            d = __builtin_elementwise_fma(hi4(wt[r][1]), hi4(h1), d);
            a = __builtin_elementwise_fma(lo4(wt[r][2]), lo4(h2), a);
            d = __builtin_elementwise_fma(hi4(wt[r][2]), hi4(h2), d);
            a = __builtin_elementwise_fma(lo4(wt[r][3]), lo4(h3), a);
            d = __builtin_elementwise_fma(hi4(wt[r][3]), hi4(h3), d);
            f32x2 s = a + d;
            float v = s.x + s.y;
            if (r == 0) acc0 = v; else if (r == 1) acc1 = v;
            else if (r == 2) acc2 = v; else acc3 = v;
        }

        // ---- DPP all-reduce across the NCH chunk lanes ----
        acc0 = dpp_addf<0xB1>(acc0); acc1 = dpp_addf<0xB1>(acc1);
        acc2 = dpp_addf<0xB1>(acc2); acc3 = dpp_addf<0xB1>(acc3);
        acc0 = dpp_addf<0x4E>(acc0); acc1 = dpp_addf<0x4E>(acc1);
        acc2 = dpp_addf<0x4E>(acc2); acc3 = dpp_addf<0x4E>(acc3);
        if constexpr (!L0) {
            acc0 = dpp_addf<0x141>(acc0); acc1 = dpp_addf<0x141>(acc1);
            acc2 = dpp_addf<0x141>(acc2); acc3 = dpp_addf<0x141>(acc3);
        }

        // ---- cell update in-place on lane kc==0 (gate order i,f,g,o) ----
        if (kc == 0) {
            float gi = acc0 + bias0;
            float gf = acc1 + bias1;
            float gg = acc2 + bias2;
            float go = acc3 + bias3;
            if constexpr (L0) {
                gi += w00 * xt; gf += w01 * xt; gg += w02 * xt; go += w03 * xt;
            }
            float i_ = fast_sigmoid(gi);
            float f_ = fast_sigmoid(gf);
            float g_ = fast_tanh(gg);
            float o_ = fast_sigmoid(go);
            c_st = f_ * c_st + i_ * g_;
            float h = o_ * fast_tanh(c_st);
            if constexpr (L0) xh[wb][(j >> 4) * 20 + (j & 15)] = h;
            else              xh[wb][80 + (j >> 4) * 20 + (j & 15)] = h;
            h_out[((long)b * T_ + t) * H_ + j] = h;
        }
        if constexpr (!L0) {
            if (kc == 1) xh[wb][(j >> 4) * 20 + (j & 15)] = xn;   // next x row
        }
        __syncthreads();
        if constexpr (L0) xt = xn;
    }
}

// MLP head (unchanged from R3; not a bottleneck): wave-uniform W1 -> s_load.
__global__ __launch_bounds__(256)
void mlp_head_v2(const float* __restrict__ hbuf,  // [B*T, H]
                 const float* __restrict__ W1,    // [H, H]
                 const float* __restrict__ b1,    // [H]
                 const float* __restrict__ W2,    // [H]
                 const float* __restrict__ b2,    // [1]
                 float* __restrict__ out)         // [B*T]
{
    const long r = (long)blockIdx.x * 256 + threadIdx.x;

    float row[H_];
    const float4* src = (const float4*)(hbuf + r * H_);
    #pragma unroll
    for (int q = 0; q < 16; ++q) {
        float4 v = src[q];
        row[4 * q + 0] = fmaxf(v.x, 0.f);
        row[4 * q + 1] = fmaxf(v.y, 0.f);
        row[4 * q + 2] = fmaxf(v.z, 0.f);
        row[4 * q + 3] = fmaxf(v.w, 0.f);
    }
    #pragma unroll
    for (int q = 0; q < 16; ++q)
        asm volatile("" : "+v"(row[4*q]), "+v"(row[4*q+1]),
                         "+v"(row[4*q+2]), "+v"(row[4*q+3]));

    float acc = b2[0];
    for (int jj = 0; jj < H_; ++jj) {
        const float* wrow = W1 + jj * H_;   // wave-uniform -> scalar loads
        float s0 = 0.f, s1 = 0.f, s2 = 0.f, s3 = 0.f;
        #pragma unroll
        for (int q = 0; q < 16; ++q) {
            s0 += row[4 * q + 0] * wrow[4 * q + 0];
            s1 += row[4 * q + 1] * wrow[4 * q + 1];
            s2 += row[4 * q + 2] * wrow[4 * q + 2];
            s3 += row[4 * q + 3] * wrow[4 * q + 3];
        }
        float y = fmaxf(b1[jj] + (s0 + s1) + (s2 + s3), 0.f);
        acc += y * W2[jj];
    }
    out[r] = acc;
}

extern "C" void kernel_launch(void* const* d_in, const int* in_sizes, int n_in,
                              void* d_out, int out_size, void* d_ws, size_t ws_size,
                              hipStream_t stream) {
    const float* x     = (const float*)d_in[0];   // [B,T,1]
    const float* w_ih0 = (const float*)d_in[1];   // [256]
    const float* w_ihr = (const float*)d_in[2];   // [4,256,64]
    const float* w_hh  = (const float*)d_in[3];   // [5,256,64]
    const float* b_ih  = (const float*)d_in[4];   // [5,256]
    const float* b_hh  = (const float*)d_in[5];   // [5,256]
    const float* W1    = (const float*)d_in[6];   // [64,64]
    const float* b1    = (const float*)d_in[7];   // [64]
    const float* W2    = (const float*)d_in[8];   // [64]
    const float* b2    = (const float*)d_in[9];   // [1]
    // d_in[10] = future (0)

    float* out = (float*)d_out;
    float* buf = (float*)d_ws;                    // [B,T,64] fp32 = 64 MB

    // layer 0 (scalar input): 256 threads (64 units x 4 chunks)
    lstm_layer_v4<true><<<dim3(B_), dim3(256), 0, stream>>>(
        x, buf, w_ih0, w_hh, b_ih, b_hh);

    // layers 1..4: 512 threads (64 units x 8 chunks), in-place on buf
    for (int l = 1; l < 5; ++l) {
        lstm_layer_v4<false><<<dim3(B_), dim3(512), 0, stream>>>(
            buf, buf,
            w_ihr + (long)(l - 1) * 4 * H_ * H_,
            w_hh  + (long)l * 4 * H_ * H_,
            b_ih  + (long)l * 4 * H_,
            b_hh  + (long)l * 4 * H_);
    }

    mlp_head_v2<<<dim3((B_ * T_) / 256), dim3(256), 0, stream>>>(
        buf, W1, b1, W2, b2, out);
}

// Round 6
// 2313.839 us; speedup vs baseline: 5.2720x; 1.2412x over previous
//
#include <hip/hip_runtime.h>

#define B_ 256
#define T_ 1024
#define H_ 64

typedef float f32x2 __attribute__((ext_vector_type(2)));
typedef float f32x4 __attribute__((ext_vector_type(4)));

// fast sigmoid/tanh via v_exp_f32 + v_rcp_f32 (validated R2-R4: absmax 0.0)
__device__ __forceinline__ float fast_sigmoid(float x) {
    float e = __builtin_amdgcn_exp2f(-1.4426950408889634f * x);
    return __builtin_amdgcn_rcpf(1.0f + e);
}
__device__ __forceinline__ float fast_tanh(float x) {
    float e = __builtin_amdgcn_exp2f(2.8853900817779268f * x);
    return 1.0f - 2.0f * __builtin_amdgcn_rcpf(1.0f + e);
}

// butterfly add via DPP: 0xB1=xor1, 0x4E=xor2, 0x141=half-mirror (=xor4 after 1,2)
template<int CTRL>
__device__ __forceinline__ float dpp_addf(float v) {
    int vi = __builtin_bit_cast(int, v);
    int sh = __builtin_amdgcn_update_dpp(0, vi, CTRL, 0xF, 0xF, true);
    return v + __builtin_bit_cast(float, sh);
}

__device__ __forceinline__ f32x2 lo4(f32x4 v) { return __builtin_shufflevector(v, v, 0, 1); }
__device__ __forceinline__ f32x2 hi4(f32x4 v) { return __builtin_shufflevector(v, v, 2, 3); }

// 4 gate rows x 16 k packed-FMA dot (identical math to R4-validated kernel)
__device__ __forceinline__ void dot4x16(const f32x4 wt[4][4],
                                        f32x4 h0, f32x4 h1, f32x4 h2, f32x4 h3,
                                        float acc[4]) {
    #pragma unroll
    for (int r = 0; r < 4; ++r) {
        f32x2 a = {0.f, 0.f}, d = {0.f, 0.f};
        a = __builtin_elementwise_fma(lo4(wt[r][0]), lo4(h0), a);
        d = __builtin_elementwise_fma(hi4(wt[r][0]), hi4(h0), d);
        a = __builtin_elementwise_fma(lo4(wt[r][1]), lo4(h1), a);
        d = __builtin_elementwise_fma(hi4(wt[r][1]), hi4(h1), d);
        a = __builtin_elementwise_fma(lo4(wt[r][2]), lo4(h2), a);
        d = __builtin_elementwise_fma(hi4(wt[r][2]), hi4(h2), d);
        a = __builtin_elementwise_fma(lo4(wt[r][3]), lo4(h3), a);
        d = __builtin_elementwise_fma(hi4(wt[r][3]), hi4(h3), d);
        f32x2 s = a + d;
        acc[r] = s.x + s.y;
    }
}

// ---------------------------------------------------------------------------
// Diagonal pair: layer A (lower) computes t=s, layer B (upper) computes t=s-1.
// A's h goes ONLY to LDS (B's x-slot); B's h goes to global. Threads [0,512)=B
// (NCH=8 over [x=h_A|h_B]), threads [512,512+TA)=A (L0: TA=256/NCH=4 over h;
// vector: TA=512/NCH=8, x prefetched from global). Chunk kc lives at float
// offset kc*20 (80B padding -> conflict-free ds_read_b128, validated R4).
// Weights asm-pinned -> AGPR-resident (R4: VGPR=52, FETCH flat).
// ---------------------------------------------------------------------------
template<bool A_L0>
__global__ __attribute__((amdgpu_flat_work_group_size(A_L0 ? 768 : 1024,
                                                      A_L0 ? 768 : 1024)))
void lstm_pair(const float* xA,                    // L0: [B,T]; else [B,T,64] (may alias hB_out)
               float* __restrict__ hB_out,         // [B,T,64]
               const float* __restrict__ wA_ih,    // L0: [256]; else [256,64]
               const float* __restrict__ wA_hh,    // [256,64]
               const float* __restrict__ bA_ih,    // [256]
               const float* __restrict__ bA_hh,    // [256]
               const float* __restrict__ wB_ih,    // [256,64]
               const float* __restrict__ wB_hh,    // [256,64]
               const float* __restrict__ bB_ih,    // [256]
               const float* __restrict__ bB_hh)    // [256]
{
    const int b   = blockIdx.x;
    const int tid = threadIdx.x;
    const bool isB = (tid < 512);

    __shared__ __align__(16) float xhA[2][A_L0 ? 80 : 160];  // A: [x|]h chunks, padded
    __shared__ __align__(16) float xhB[2][160];              // B: [h_A | h_B] chunks

    // ---------------- per-role setup ----------------
    int kc, j;
    f32x4 wt[4][4];
    float bias0 = 0.f, bias1 = 0.f, bias2 = 0.f, bias3 = 0.f;
    float w00 = 0.f, w01 = 0.f, w02 = 0.f, w03 = 0.f;   // L0 scalar-x weights

    if (isB) {
        kc = tid & 7; j = tid >> 3;
        #pragma unroll
        for (int r = 0; r < 4; ++r) {
            const int row = r * H_ + j;
            const float* base = (kc < 4) ? (wB_ih + row * H_ + kc * 16)
                                         : (wB_hh + row * H_ + (kc - 4) * 16);
            #pragma unroll
            for (int q = 0; q < 4; ++q) wt[r][q] = *(const f32x4*)(base + 4 * q);
        }
        if (kc == 0) {
            bias0 = bB_ih[0*H_+j] + bB_hh[0*H_+j];
            bias1 = bB_ih[1*H_+j] + bB_hh[1*H_+j];
            bias2 = bB_ih[2*H_+j] + bB_hh[2*H_+j];
            bias3 = bB_ih[3*H_+j] + bB_hh[3*H_+j];
        }
    } else {
        const int t2 = tid - 512;
        if (A_L0) { kc = t2 & 3; j = t2 >> 2; }
        else      { kc = t2 & 7; j = t2 >> 3; }
        #pragma unroll
        for (int r = 0; r < 4; ++r) {
            const int row = r * H_ + j;
            const float* base;
            if (A_L0)         base = wA_hh + row * H_ + kc * 16;
            else if (kc < 4)  base = wA_ih + row * H_ + kc * 16;
            else              base = wA_hh + row * H_ + (kc - 4) * 16;
            #pragma unroll
            for (int q = 0; q < 4; ++q) wt[r][q] = *(const f32x4*)(base + 4 * q);
        }
        if (kc == 0) {
            bias0 = bA_ih[0*H_+j] + bA_hh[0*H_+j];
            bias1 = bA_ih[1*H_+j] + bA_hh[1*H_+j];
            bias2 = bA_ih[2*H_+j] + bA_hh[2*H_+j];
            bias3 = bA_ih[3*H_+j] + bA_hh[3*H_+j];
            if (A_L0) {
                w00 = wA_ih[0*H_+j]; w01 = wA_ih[1*H_+j];
                w02 = wA_ih[2*H_+j]; w03 = wA_ih[3*H_+j];
            }
        }
    }
    #pragma unroll
    for (int r = 0; r < 4; ++r)
        #pragma unroll
        for (int q = 0; q < 4; ++q)
            asm volatile("" : "+v"(wt[r][q]));

    float c_st = 0.f;
    float xt = (!isB && A_L0) ? xA[(long)b * T_] : 0.f;

    // ---------------- LDS init ----------------
    if (isB) {
        if (tid < H_) xhB[1][80 + (tid >> 4) * 20 + (tid & 15)] = 0.f;  // h_B[-1]=0
    } else {
        const int t2 = tid - 512;
        if (t2 < H_) {
            const int off = (t2 >> 4) * 20 + (t2 & 15);
            if (A_L0) {
                xhA[0][off] = 0.f;                                   // h_A[-1]=0
            } else {
                xhA[0][off]      = xA[((long)b * T_) * H_ + t2];     // x row 0
                xhA[0][80 + off] = 0.f;                              // h_A[-1]=0
            }
        }
    }
    __syncthreads();

    // ---------------- diagonal steps ----------------
    for (int s = 0; s <= T_; ++s) {
        const int rb = s & 1, wb = rb ^ 1;

        if (isB) {
            if (s >= 1) {
                const f32x4* xv = (const f32x4*)&xhB[rb][kc * 20];
                f32x4 h0 = xv[0], h1 = xv[1], h2 = xv[2], h3 = xv[3];
                float acc[4];
                dot4x16(wt, h0, h1, h2, h3, acc);
                acc[0] = dpp_addf<0xB1>(acc[0]); acc[1] = dpp_addf<0xB1>(acc[1]);
                acc[2] = dpp_addf<0xB1>(acc[2]); acc[3] = dpp_addf<0xB1>(acc[3]);
                acc[0] = dpp_addf<0x4E>(acc[0]); acc[1] = dpp_addf<0x4E>(acc[1]);
                acc[2] = dpp_addf<0x4E>(acc[2]); acc[3] = dpp_addf<0x4E>(acc[3]);
                acc[0] = dpp_addf<0x141>(acc[0]); acc[1] = dpp_addf<0x141>(acc[1]);
                acc[2] = dpp_addf<0x141>(acc[2]); acc[3] = dpp_addf<0x141>(acc[3]);
                if (kc == 0) {
                    float i_ = fast_sigmoid(acc[0] + bias0);
                    float f_ = fast_sigmoid(acc[1] + bias1);
                    float g_ = fast_tanh   (acc[2] + bias2);
                    float o_ = fast_sigmoid(acc[3] + bias3);
                    c_st = f_ * c_st + i_ * g_;
                    float h = o_ * fast_tanh(c_st);
                    xhB[wb][80 + (j >> 4) * 20 + (j & 15)] = h;
                    hB_out[((long)b * T_ + (s - 1)) * H_ + j] = h;
                }
            }
        } else {
            if (s < T_) {
                float xn = 0.f;
                if (A_L0) {
                    if (s + 1 < T_) xn = xA[(long)b * T_ + s + 1];   // uniform
                } else {
                    if (kc == 1 && s + 1 < T_)
                        xn = xA[((long)b * T_ + s + 1) * H_ + j];
                }
                const f32x4* xv = (const f32x4*)&xhA[rb][kc * 20];
                f32x4 h0 = xv[0], h1 = xv[1], h2 = xv[2], h3 = xv[3];
                float acc[4];
                dot4x16(wt, h0, h1, h2, h3, acc);
                acc[0] = dpp_addf<0xB1>(acc[0]); acc[1] = dpp_addf<0xB1>(acc[1]);
                acc[2] = dpp_addf<0xB1>(acc[2]); acc[3] = dpp_addf<0xB1>(acc[3]);
                acc[0] = dpp_addf<0x4E>(acc[0]); acc[1] = dpp_addf<0x4E>(acc[1]);
                acc[2] = dpp_addf<0x4E>(acc[2]); acc[3] = dpp_addf<0x4E>(acc[3]);
                if constexpr (!A_L0) {
                    acc[0] = dpp_addf<0x141>(acc[0]); acc[1] = dpp_addf<0x141>(acc[1]);
                    acc[2] = dpp_addf<0x141>(acc[2]); acc[3] = dpp_addf<0x141>(acc[3]);
                }
                if (kc == 0) {
                    float gi = acc[0] + bias0, gf = acc[1] + bias1;
                    float gg = acc[2] + bias2, go = acc[3] + bias3;
                    if constexpr (A_L0) {
                        gi += w00 * xt; gf += w01 * xt; gg += w02 * xt; go += w03 * xt;
                    }
                    float i_ = fast_sigmoid(gi);
                    float f_ = fast_sigmoid(gf);
                    float g_ = fast_tanh(gg);
                    float o_ = fast_sigmoid(go);
                    c_st = f_ * c_st + i_ * g_;
                    float h = o_ * fast_tanh(c_st);
                    const int off = (j >> 4) * 20 + (j & 15);
                    if constexpr (A_L0) xhA[wb][off] = h;
                    else                xhA[wb][80 + off] = h;
                    xhB[wb][off] = h;                      // feed B's x-slot
                }
                if constexpr (!A_L0) {
                    if (kc == 1) xhA[wb][(j >> 4) * 20 + (j & 15)] = xn;
                }
                if constexpr (A_L0) xt = xn;
            }
        }
        __syncthreads();
    }
}

// ---------------------------------------------------------------------------
// Single layer (R4-validated, 649 us): used for L4.
// ---------------------------------------------------------------------------
template<bool L0>
__global__ __attribute__((amdgpu_flat_work_group_size(L0 ? 256 : 512, L0 ? 256 : 512),
                          amdgpu_waves_per_eu(2)))
void lstm_layer_v4(const float* x_in,
                   float* h_out,
                   const float* __restrict__ w_ih,
                   const float* __restrict__ w_hh,
                   const float* __restrict__ b_ih,
                   const float* __restrict__ b_hh)
{
    constexpr int NCH = L0 ? 4 : 8;
    const int b   = blockIdx.x;
    const int tid = threadIdx.x;
    const int kc  = tid & (NCH - 1);
    const int j   = tid >> (L0 ? 2 : 3);

    __shared__ __align__(16) float xh[2][NCH * 20];

    f32x4 wt[4][4];
    #pragma unroll
    for (int r = 0; r < 4; ++r) {
        const int row = r * H_ + j;
        const float* base;
        if (L0)           base = w_hh + row * H_ + kc * 16;
        else if (kc < 4)  base = w_ih + row * H_ + kc * 16;
        else              base = w_hh + row * H_ + (kc - 4) * 16;
        #pragma unroll
        for (int q = 0; q < 4; ++q)
            wt[r][q] = *(const f32x4*)(base + 4 * q);
    }
    #pragma unroll
    for (int r = 0; r < 4; ++r)
        #pragma unroll
        for (int q = 0; q < 4; ++q)
            asm volatile("" : "+v"(wt[r][q]));

    float bias0 = 0.f, bias1 = 0.f, bias2 = 0.f, bias3 = 0.f;
    float w00 = 0.f, w01 = 0.f, w02 = 0.f, w03 = 0.f;
    if (kc == 0) {
        bias0 = b_ih[0*H_+j] + b_hh[0*H_+j];
        bias1 = b_ih[1*H_+j] + b_hh[1*H_+j];
        bias2 = b_ih[2*H_+j] + b_hh[2*H_+j];
        bias3 = b_ih[3*H_+j] + b_hh[3*H_+j];
        if (L0) {
            w00 = w_ih[0*H_+j]; w01 = w_ih[1*H_+j];
            w02 = w_ih[2*H_+j]; w03 = w_ih[3*H_+j];
        }
    }
    float c_st = 0.f;
    float xt = L0 ? x_in[(long)b * T_] : 0.f;

    if (tid < H_) {
        if (L0) {
            xh[0][(tid >> 4) * 20 + (tid & 15)] = 0.f;
        } else {
            xh[0][(tid >> 4) * 20 + (tid & 15)] = x_in[((long)b * T_) * H_ + tid];
            xh[0][80 + (tid >> 4) * 20 + (tid & 15)] = 0.f;
        }
    }
    __syncthreads();

    for (int t = 0; t < T_; ++t) {
        const int rb = t & 1, wb = rb ^ 1;

        float xn = 0.f;
        if (L0) {
            if (t + 1 < T_) xn = x_in[(long)b * T_ + t + 1];
        } else {
            if (kc == 1 && t + 1 < T_)
                xn = x_in[((long)b * T_ + t + 1) * H_ + j];
        }

        const f32x4* xv = (const f32x4*)&xh[rb][kc * 20];
        f32x4 h0 = xv[0], h1 = xv[1], h2 = xv[2], h3 = xv[3];
        float acc[4];
        dot4x16(wt, h0, h1, h2, h3, acc);

        acc[0] = dpp_addf<0xB1>(acc[0]); acc[1] = dpp_addf<0xB1>(acc[1]);
        acc[2] = dpp_addf<0xB1>(acc[2]); acc[3] = dpp_addf<0xB1>(acc[3]);
        acc[0] = dpp_addf<0x4E>(acc[0]); acc[1] = dpp_addf<0x4E>(acc[1]);
        acc[2] = dpp_addf<0x4E>(acc[2]); acc[3] = dpp_addf<0x4E>(acc[3]);
        if constexpr (!L0) {
            acc[0] = dpp_addf<0x141>(acc[0]); acc[1] = dpp_addf<0x141>(acc[1]);
            acc[2] = dpp_addf<0x141>(acc[2]); acc[3] = dpp_addf<0x141>(acc[3]);
        }

        if (kc == 0) {
            float gi = acc[0] + bias0, gf = acc[1] + bias1;
            float gg = acc[2] + bias2, go = acc[3] + bias3;
            if constexpr (L0) {
                gi += w00 * xt; gf += w01 * xt; gg += w02 * xt; go += w03 * xt;
            }
            float i_ = fast_sigmoid(gi);
            float f_ = fast_sigmoid(gf);
            float g_ = fast_tanh(gg);
            float o_ = fast_sigmoid(go);
            c_st = f_ * c_st + i_ * g_;
            float h = o_ * fast_tanh(c_st);
            if constexpr (L0) xh[wb][(j >> 4) * 20 + (j & 15)] = h;
            else              xh[wb][80 + (j >> 4) * 20 + (j & 15)] = h;
            h_out[((long)b * T_ + t) * H_ + j] = h;
        }
        if constexpr (!L0) {
            if (kc == 1) xh[wb][(j >> 4) * 20 + (j & 15)] = xn;
        }
        __syncthreads();
        if constexpr (L0) xt = xn;
    }
}

// MLP head (R3/R4-validated): wave-uniform W1 -> scalar loads.
__global__ __launch_bounds__(256)
void mlp_head_v2(const float* __restrict__ hbuf,
                 const float* __restrict__ W1,
                 const float* __restrict__ b1,
                 const float* __restrict__ W2,
                 const float* __restrict__ b2,
                 float* __restrict__ out)
{
    const long r = (long)blockIdx.x * 256 + threadIdx.x;

    float row[H_];
    const float4* src = (const float4*)(hbuf + r * H_);
    #pragma unroll
    for (int q = 0; q < 16; ++q) {
        float4 v = src[q];
        row[4*q+0] = fmaxf(v.x, 0.f); row[4*q+1] = fmaxf(v.y, 0.f);
        row[4*q+2] = fmaxf(v.z, 0.f); row[4*q+3] = fmaxf(v.w, 0.f);
    }
    #pragma unroll
    for (int q = 0; q < 16; ++q)
        asm volatile("" : "+v"(row[4*q]), "+v"(row[4*q+1]),
                         "+v"(row[4*q+2]), "+v"(row[4*q+3]));

    float acc = b2[0];
    for (int jj = 0; jj < H_; ++jj) {
        const float* wrow = W1 + jj * H_;
        float s0 = 0.f, s1 = 0.f, s2 = 0.f, s3 = 0.f;
        #pragma unroll
        for (int q = 0; q < 16; ++q) {
            s0 += row[4*q+0] * wrow[4*q+0];
            s1 += row[4*q+1] * wrow[4*q+1];
            s2 += row[4*q+2] * wrow[4*q+2];
            s3 += row[4*q+3] * wrow[4*q+3];
        }
        float y = fmaxf(b1[jj] + (s0 + s1) + (s2 + s3), 0.f);
        acc += y * W2[jj];
    }
    out[r] = acc;
}

extern "C" void kernel_launch(void* const* d_in, const int* in_sizes, int n_in,
                              void* d_out, int out_size, void* d_ws, size_t ws_size,
                              hipStream_t stream) {
    const float* x     = (const float*)d_in[0];   // [B,T,1]
    const float* w_ih0 = (const float*)d_in[1];   // [256]
    const float* w_ihr = (const float*)d_in[2];   // [4,256,64]
    const float* w_hh  = (const float*)d_in[3];   // [5,256,64]
    const float* b_ih  = (const float*)d_in[4];   // [5,256]
    const float* b_hh  = (const float*)d_in[5];   // [5,256]
    const float* W1    = (const float*)d_in[6];   // [64,64]
    const float* b1    = (const float*)d_in[7];   // [64]
    const float* W2    = (const float*)d_in[8];   // [64]
    const float* b2    = (const float*)d_in[9];   // [1]
    // d_in[10] = future (0)

    float* out = (float*)d_out;
    float* buf = (float*)d_ws;                    // [B,T,64] fp32 = 64 MB

    const long LW = 4L * H_ * H_;   // 16384 floats per layer weight block
    const long LB = 4L * H_;        // 256 floats per layer bias block

    // K1: [L0 + L1] diagonal pair -> buf = h_L1
    lstm_pair<true><<<dim3(B_), dim3(768), 0, stream>>>(
        x, buf,
        w_ih0,            w_hh + 0 * LW, b_ih + 0 * LB, b_hh + 0 * LB,
        w_ihr + 0 * LW,   w_hh + 1 * LW, b_ih + 1 * LB, b_hh + 1 * LB);

    // K2: [L2 + L3] diagonal pair, in-place on buf -> buf = h_L3
    lstm_pair<false><<<dim3(B_), dim3(1024), 0, stream>>>(
        buf, buf,
        w_ihr + 1 * LW,   w_hh + 2 * LW, b_ih + 2 * LB, b_hh + 2 * LB,
        w_ihr + 2 * LW,   w_hh + 3 * LW, b_ih + 3 * LB, b_hh + 3 * LB);

    // K3: L4 single (R4 kernel), in-place -> buf = h_L4
    lstm_layer_v4<false><<<dim3(B_), dim3(512), 0, stream>>>(
        buf, buf,
        w_ihr + 3 * LW,   w_hh + 4 * LW, b_ih + 4 * LB, b_hh + 4 * LB);

    mlp_head_v2<<<dim3((B_ * T_) / 256), dim3(256), 0, stream>>>(
        buf, W1, b1, W2, b2, out);
}